// Round 3
// baseline (2027.732 us; speedup 1.0000x reference)
//
#include <hip/hip_runtime.h>
#include <cmath>

#define NSP 1728   // 12*12*12
#define BB  2      // batch
#define SS  12

typedef __attribute__((ext_vector_type(8))) short short8;
typedef __attribute__((ext_vector_type(4))) short short4v;
typedef __attribute__((ext_vector_type(4))) float floatx4;

__device__ __forceinline__ short f2bf(float f) {
    unsigned u = __float_as_uint(f);
    u += 0x7fff + ((u >> 16) & 1);
    return (short)(u >> 16);
}
__device__ __forceinline__ short8 ld8(const short* p) {
    short4v a = *(const short4v*)p;
    short4v b = *(const short4v*)(p + 4);
    return __builtin_shufflevector(a, b, 0, 1, 2, 3, 4, 5, 6, 7);
}

// ---------------- block-wide dual reduction (sum, sumsq) -------------------
__device__ __forceinline__ void block_reduce2(float& s, float& s2) {
    __shared__ float red[8][2];
    __syncthreads();                 // protect red[] reuse across calls
    #pragma unroll
    for (int o = 32; o; o >>= 1) {
        s  += __shfl_down(s,  o, 64);
        s2 += __shfl_down(s2, o, 64);
    }
    int lane = threadIdx.x & 63, w = threadIdx.x >> 6;
    if (lane == 0) { red[w][0] = s; red[w][1] = s2; }
    __syncthreads();
    int nw = (blockDim.x + 63) >> 6;
    if (threadIdx.x == 0) {
        float a = 0.f, b = 0.f;
        for (int i = 0; i < nw; i++) { a += red[i][0]; b += red[i][1]; }
        red[0][0] = a; red[0][1] = b;
    }
    __syncthreads();
    s = red[0][0]; s2 = red[0][1];
}

// ======= MBConv stage 1: expand conv + IN + SiLU + dw3x3x3 + IN + SiLU + SE-squeeze
// grid: b * (C/2) blocks of 256; block owns 2 output channels, full n.
__global__ __launch_bounds__(256) void mbk1_kernel(
        const float* __restrict__ in,   // [b, Cin, NSP]
        const float* __restrict__ ew,   // [C, Cin]
        const float* __restrict__ g1, const float* __restrict__ b1,
        const float* __restrict__ dw,   // [C,27]
        const float* __restrict__ g2, const float* __restrict__ b2,
        float* __restrict__ out,        // [b, C, NSP]
        float* __restrict__ se_s,       // [b*C]
        int Cin, int C) {
    int nct = C >> 1;
    int b = blockIdx.x / nct, ct = blockIdx.x % nct;
    int c0 = ct * 2;
    __shared__ float wl[2 * 128];         // [ci][2]
    __shared__ float tile[2][NSP];
    __shared__ float wsh[2][27];
    const float* ip = in + (size_t)b * Cin * NSP;
    for (int idx = threadIdx.x; idx < Cin * 2; idx += 256) {
        int k = idx / Cin, ci = idx - k * Cin;
        wl[ci * 2 + k] = ew[(size_t)(c0 + k) * Cin + ci];
    }
    if (threadIdx.x < 54)
        wsh[threadIdx.x / 27][threadIdx.x % 27] = dw[(size_t)(c0 + threadIdx.x / 27) * 27 + threadIdx.x % 27];
    __syncthreads();
    float r0[7], r1[7];
    #pragma unroll
    for (int i = 0; i < 7; i++) { r0[i] = 0.f; r1[i] = 0.f; }
    #pragma unroll 2
    for (int ci = 0; ci < Cin; ci++) {
        float w0 = wl[ci * 2], w1 = wl[ci * 2 + 1];
        const float* xp = ip + (size_t)ci * NSP + threadIdx.x;
        #pragma unroll
        for (int i = 0; i < 7; i++) {
            int n = threadIdx.x + i * 256;
            if (n < NSP) {
                float xv = xp[i * 256];
                r0[i] = fmaf(w0, xv, r0[i]);
                r1[i] = fmaf(w1, xv, r1[i]);
            }
        }
    }
    // InstanceNorm + SiLU per channel -> LDS tile
    #pragma unroll
    for (int ch = 0; ch < 2; ch++) {
        float* r = ch ? r1 : r0;
        float s = 0.f, s2 = 0.f;
        #pragma unroll
        for (int i = 0; i < 7; i++) {
            int n = threadIdx.x + i * 256;
            if (n < NSP) { s += r[i]; s2 += r[i] * r[i]; }
        }
        block_reduce2(s, s2);
        float mean = s / NSP, var = s2 / NSP - (s / NSP) * (s / NSP);
        float rstd = rsqrtf(var + 1e-5f);
        float gc = g1[c0 + ch], bc = b1[c0 + ch];
        #pragma unroll
        for (int i = 0; i < 7; i++) {
            int n = threadIdx.x + i * 256;
            if (n < NSP) {
                float v = (r[i] - mean) * rstd * gc + bc;
                tile[ch][n] = v / (1.f + __expf(-v));
            }
        }
    }
    __syncthreads();
    // depthwise 3x3x3
    float d0[7], d1[7];
    #pragma unroll
    for (int i = 0; i < 7; i++) {
        int n = threadIdx.x + i * 256;
        d0[i] = 0.f; d1[i] = 0.f;
        if (n < NSP) {
            int z = n / 144, y = (n / 12) % 12, x = n % 12;
            #pragma unroll
            for (int dz = -1; dz <= 1; dz++) {
                int zz = z + dz; if (zz < 0 || zz >= SS) continue;
                #pragma unroll
                for (int dy = -1; dy <= 1; dy++) {
                    int yy = y + dy; if (yy < 0 || yy >= SS) continue;
                    #pragma unroll
                    for (int dx = -1; dx <= 1; dx++) {
                        int xx = x + dx; if (xx < 0 || xx >= SS) continue;
                        int t = (zz * 12 + yy) * 12 + xx;
                        float wv0 = wsh[0][(dz + 1) * 9 + (dy + 1) * 3 + (dx + 1)];
                        float wv1 = wsh[1][(dz + 1) * 9 + (dy + 1) * 3 + (dx + 1)];
                        d0[i] = fmaf(wv0, tile[0][t], d0[i]);
                        d1[i] = fmaf(wv1, tile[1][t], d1[i]);
                    }
                }
            }
        }
    }
    // IN + SiLU + write + SE squeeze
    float se0 = 0.f, se1 = 0.f;
    #pragma unroll
    for (int ch = 0; ch < 2; ch++) {
        float* d = ch ? d1 : d0;
        float s = 0.f, s2 = 0.f;
        #pragma unroll
        for (int i = 0; i < 7; i++) {
            int n = threadIdx.x + i * 256;
            if (n < NSP) { s += d[i]; s2 += d[i] * d[i]; }
        }
        block_reduce2(s, s2);
        float mean = s / NSP, var = s2 / NSP - (s / NSP) * (s / NSP);
        float rstd = rsqrtf(var + 1e-5f);
        float gc = g2[c0 + ch], bc = b2[c0 + ch];
        float ss = 0.f;
        float* op = out + ((size_t)b * C + c0 + ch) * NSP;
        #pragma unroll
        for (int i = 0; i < 7; i++) {
            int n = threadIdx.x + i * 256;
            if (n < NSP) {
                float v = (d[i] - mean) * rstd * gc + bc;
                v = v / (1.f + __expf(-v));
                op[n] = v;
                ss += v;
            }
        }
        if (ch) se1 = ss; else se0 = ss;
    }
    block_reduce2(se0, se1);
    if (threadIdx.x == 0) {
        se_s[b * C + c0]     = se0 / NSP;
        se_s[b * C + c0 + 1] = se1 / NSP;
    }
}

// ---------------- SE: fc1+silu, fc2+sigmoid --------------------------------
__global__ void se_kernel(const float* __restrict__ s,
                          const float* __restrict__ w1, const float* __restrict__ b1,
                          const float* __restrict__ w2, const float* __restrict__ b2,
                          float* __restrict__ gate, int C, int R) {
    __shared__ float sh_s[512];
    __shared__ float sh_h[128];
    int b = blockIdx.x;
    for (int c = threadIdx.x; c < C; c += blockDim.x) sh_s[c] = s[b * C + c];
    __syncthreads();
    for (int r = threadIdx.x; r < R; r += blockDim.x) {
        float a = b1[r];
        for (int c = 0; c < C; c++) a = fmaf(w1[(size_t)r * C + c], sh_s[c], a);
        sh_h[r] = a / (1.f + __expf(-a));
    }
    __syncthreads();
    for (int c = threadIdx.x; c < C; c += blockDim.x) {
        float a = b2[c];
        for (int r = 0; r < R; r++) a = fmaf(w2[(size_t)c * R + r], sh_h[r], a);
        gate[b * C + c] = 1.f / (1.f + __expf(-a));
    }
}

// ======= Full-n 1x1 conv: 1 co per block, optional SE-gate fold, bias,
//         optional InstanceNorm, optional residual, optional raw-stats emit.
__global__ __launch_bounds__(256) void convfull_kernel(
        const float* __restrict__ in, const float* __restrict__ w,
        const float* __restrict__ bias, const float* __restrict__ se_gate,
        const float* __restrict__ resid,
        const float* __restrict__ ng, const float* __restrict__ nb, int do_norm,
        float* __restrict__ out, float* __restrict__ stats_out,
        int Cin, int Cout) {
    extern __shared__ float wl[];       // [Cin]
    int b = blockIdx.x / Cout, co = blockIdx.x % Cout;
    const float* gp = se_gate ? se_gate + (size_t)b * Cin : nullptr;
    const float* wrow = w + (size_t)co * Cin;
    for (int ci = threadIdx.x; ci < Cin; ci += 256)
        wl[ci] = wrow[ci] * (gp ? gp[ci] : 1.f);
    __syncthreads();
    const float* ip = in + (size_t)b * Cin * NSP;
    float rx[4] = {0.f, 0.f, 0.f, 0.f}, ry[4] = {0.f, 0.f, 0.f, 0.f};
    #pragma unroll 4
    for (int ci = 0; ci < Cin; ci++) {
        float wv = wl[ci];
        const float* p = ip + (size_t)ci * NSP;
        #pragma unroll
        for (int ch = 0; ch < 4; ch++) {
            int n = ch * 512 + threadIdx.x * 2;
            if (n < NSP) {
                float2 v = *(const float2*)(p + n);
                rx[ch] = fmaf(wv, v.x, rx[ch]);
                ry[ch] = fmaf(wv, v.y, ry[ch]);
            }
        }
    }
    float bv = bias ? bias[co] : 0.f;
    #pragma unroll
    for (int ch = 0; ch < 4; ch++) { rx[ch] += bv; ry[ch] += bv; }
    float mean = 0.f, rstd = 1.f;
    if (do_norm) {
        float s = 0.f, s2 = 0.f;
        #pragma unroll
        for (int ch = 0; ch < 4; ch++) {
            int n = ch * 512 + threadIdx.x * 2;
            if (n < NSP) { s += rx[ch] + ry[ch]; s2 += rx[ch] * rx[ch] + ry[ch] * ry[ch]; }
        }
        block_reduce2(s, s2);
        mean = s / NSP;
        float var = s2 / NSP - mean * mean;
        rstd = rsqrtf(var + 1e-5f);
    }
    float gc = do_norm ? ng[co] : 1.f, bc = do_norm ? nb[co] : 0.f;
    size_t obase = ((size_t)b * Cout + co) * NSP;
    float s = 0.f, s2 = 0.f;
    #pragma unroll
    for (int ch = 0; ch < 4; ch++) {
        int n = ch * 512 + threadIdx.x * 2;
        if (n < NSP) {
            float vx = do_norm ? (rx[ch] - mean) * rstd * gc + bc : rx[ch];
            float vy = do_norm ? (ry[ch] - mean) * rstd * gc + bc : ry[ch];
            if (resid) { vx += resid[obase + n]; vy += resid[obase + n + 1]; }
            float2 o; o.x = vx; o.y = vy;
            *(float2*)(out + obase + n) = o;
            s += vx + vy; s2 += vx * vx + vy * vy;
        }
    }
    if (stats_out) {
        block_reduce2(s, s2);
        if (threadIdx.x == 0) {
            stats_out[(b * Cout + co) * 2]     = s;
            stats_out[(b * Cout + co) * 2 + 1] = s2;
        }
    }
}

// ======= GroupNorm-fold: scale[b,Cin] = rstd*gamma ; biasb[b,o] = bias_in[o] + sum_ci W*shift
__global__ void gfold_kernel(const float* __restrict__ rawstats,
                             const float* __restrict__ gamma, const float* __restrict__ beta,
                             const float* __restrict__ W, const float* __restrict__ bias_in,
                             float* __restrict__ scale, float* __restrict__ biasb,
                             int Cin, int Cout, int gs) {
    int nct = Cout / 64;
    int b = blockIdx.x / nct, ot = blockIdx.x % nct;
    __shared__ float sshift[128];
    for (int ci = threadIdx.x; ci < Cin; ci += 64) {
        int g0 = ci / gs;
        float S = 0.f, S2 = 0.f;
        for (int k = 0; k < gs; k++) {
            S  += rawstats[(b * Cin + g0 * gs + k) * 2];
            S2 += rawstats[(b * Cin + g0 * gs + k) * 2 + 1];
        }
        float N = gs * (float)NSP;
        float mean = S / N, var = S2 / N - mean * mean;
        float r = rsqrtf(var + 1e-5f);
        float sc = r * gamma[ci];
        sshift[ci] = beta[ci] - mean * sc;
        if (ot == 0) scale[b * Cin + ci] = sc;
    }
    __syncthreads();
    int o = ot * 64 + threadIdx.x;
    float acc = bias_in ? bias_in[o] : 0.f;
    for (int ci = 0; ci < Cin; ci++)
        acc = fmaf(W[(size_t)o * Cin + ci], sshift[ci], acc);
    biasb[b * Cout + o] = acc;
}

// ======= Split-n 1x1 conv (4 co per block, y n-tiles of 432), gate + per-b bias, opt GELU
__global__ __launch_bounds__(256) void convsplit_kernel(
        const float* __restrict__ in, const float* __restrict__ w,
        const float* __restrict__ biasb,  // [b, Cout]
        const float* __restrict__ gate,   // [b, Cin]
        float* __restrict__ out, int Cin, int Cout, int act) {
    int ncot = Cout >> 2;
    int b = blockIdx.x / ncot, ct = blockIdx.x % ncot;
    int co0 = ct << 2;
    extern __shared__ float wl[];         // [Cin][4]
    const float* wsrc = w + (size_t)co0 * Cin;
    const float* gp = gate ? gate + (size_t)b * Cin : nullptr;
    for (int idx = threadIdx.x; idx < Cin * 4; idx += 256) {
        int k = idx / Cin, ci = idx - k * Cin;
        float v = wsrc[idx];
        if (gp) v *= gp[ci];
        wl[ci * 4 + k] = v;
    }
    __syncthreads();
    if (threadIdx.x >= 216) return;
    int n0 = blockIdx.y * 432 + threadIdx.x * 2;
    const float* ip = in + (size_t)b * Cin * NSP + n0;
    float ax0 = 0.f, ax1 = 0.f, ax2 = 0.f, ax3 = 0.f;
    float ay0 = 0.f, ay1 = 0.f, ay2 = 0.f, ay3 = 0.f;
    #pragma unroll 4
    for (int ci = 0; ci < Cin; ci++) {
        float2 iv = *(const float2*)(ip + (size_t)ci * NSP);
        float4 wv = *(const float4*)(wl + ci * 4);
        ax0 = fmaf(wv.x, iv.x, ax0); ay0 = fmaf(wv.x, iv.y, ay0);
        ax1 = fmaf(wv.y, iv.x, ax1); ay1 = fmaf(wv.y, iv.y, ay1);
        ax2 = fmaf(wv.z, iv.x, ax2); ay2 = fmaf(wv.z, iv.y, ay2);
        ax3 = fmaf(wv.w, iv.x, ax3); ay3 = fmaf(wv.w, iv.y, ay3);
    }
    float accx[4] = {ax0, ax1, ax2, ax3};
    float accy[4] = {ay0, ay1, ay2, ay3};
    #pragma unroll
    for (int k = 0; k < 4; k++) {
        int co = co0 + k;
        float bx = accx[k] + biasb[b * Cout + co];
        float by = accy[k] + biasb[b * Cout + co];
        if (act == 2) {
            bx = 0.5f * bx * (1.f + erff(bx * 0.70710678118654752f));
            by = 0.5f * by * (1.f + erff(by * 0.70710678118654752f));
        }
        size_t oi = ((size_t)b * Cout + co) * NSP + n0;
        float2 o; o.x = bx; o.y = by;
        *(float2*)(out + oi) = o;
    }
}

// ======= MFMA flash attention =======
// grid (16 bh, 27 mblocks), 256 thr = 4 waves; wave owns 16 queries.
// qkv: [b][(t*8+h)*16+d][n]; out: [b][h*16+d][n]
#define KTP 20
#define VTP 196
#define PTP 36
__global__ __launch_bounds__(256) void attn_mfma_kernel(const float* __restrict__ qkv,
                                                        float* __restrict__ out) {
    __shared__ __align__(16) short kt[192 * KTP];
    __shared__ __align__(16) short vt[16 * VTP];
    __shared__ __align__(16) short pt[4][16 * PTP];
    int bh = blockIdx.x;
    int b = bh >> 3, h = bh & 7;
    const float* base = qkv + (size_t)b * 384 * NSP;
    const float* qp = base + (size_t)(h * 16) * NSP;
    const float* kp = base + (size_t)(128 + h * 16) * NSP;
    const float* vp = base + (size_t)(256 + h * 16) * NSP;
    int wave = threadIdx.x >> 6, lane = threadIdx.x & 63;
    int m = lane & 15, quad = lane >> 4;
    int q0 = (blockIdx.y * 4 + wave) * 16;
    short* ptw = pt[wave];
    // Q A-frag: A[m][k=quad*8+i], k<16 valid (quads 0,1), scale 0.25 folded
    short8 qa;
    #pragma unroll
    for (int i = 0; i < 8; i++) qa[i] = 0;
    if (quad < 2) {
        #pragma unroll
        for (int i = 0; i < 8; i++) {
            int d = quad * 8 + i;
            qa[i] = f2bf(qp[(size_t)d * NSP + q0 + m] * 0.25f);
        }
    }
    floatx4 o0 = {0.f, 0.f, 0.f, 0.f};
    float ls0 = 0.f, ls1 = 0.f, ls2 = 0.f, ls3 = 0.f;
    for (int jc = 0; jc < 9; jc++) {
        int j0 = jc * 192;
        __syncthreads();
        for (int idx = threadIdx.x; idx < 3072; idx += 256) {
            int d = idx / 192, j = idx - d * 192;
            kt[j * KTP + d] = f2bf(kp[(size_t)d * NSP + j0 + j]);
            vt[d * VTP + j] = f2bf(vp[(size_t)d * NSP + j0 + j]);
        }
        __syncthreads();
        for (int s = 0; s < 6; s++) {
            int jl = s * 32;
            short8 bk0, bk1;
            #pragma unroll
            for (int i = 0; i < 8; i++) { bk0[i] = 0; bk1[i] = 0; }
            if (quad < 2) {
                bk0 = ld8(kt + (jl + m) * KTP + quad * 8);
                bk1 = ld8(kt + (jl + 16 + m) * KTP + quad * 8);
            }
            floatx4 s0 = {0.f, 0.f, 0.f, 0.f}, s1 = {0.f, 0.f, 0.f, 0.f};
            s0 = __builtin_amdgcn_mfma_f32_16x16x32_bf16(qa, bk0, s0, 0, 0, 0);
            s1 = __builtin_amdgcn_mfma_f32_16x16x32_bf16(qa, bk1, s1, 0, 0, 0);
            float p00 = __expf(s0[0]), p01 = __expf(s0[1]), p02 = __expf(s0[2]), p03 = __expf(s0[3]);
            float p10 = __expf(s1[0]), p11 = __expf(s1[1]), p12 = __expf(s1[2]), p13 = __expf(s1[3]);
            ls0 += p00 + p10; ls1 += p01 + p11; ls2 += p02 + p12; ls3 += p03 + p13;
            int rw = quad * 4;
            ptw[(rw + 0) * PTP + m] = f2bf(p00);
            ptw[(rw + 1) * PTP + m] = f2bf(p01);
            ptw[(rw + 2) * PTP + m] = f2bf(p02);
            ptw[(rw + 3) * PTP + m] = f2bf(p03);
            ptw[(rw + 0) * PTP + 16 + m] = f2bf(p10);
            ptw[(rw + 1) * PTP + 16 + m] = f2bf(p11);
            ptw[(rw + 2) * PTP + 16 + m] = f2bf(p12);
            ptw[(rw + 3) * PTP + 16 + m] = f2bf(p13);
            short8 pa = ld8(ptw + m * PTP + quad * 8);
            short8 vb = ld8(vt + m * VTP + jl + quad * 8);
            o0 = __builtin_amdgcn_mfma_f32_16x16x32_bf16(pa, vb, o0, 0, 0, 0);
        }
    }
    // reduce l across the 16 lanes of each quad
    float L[4] = {ls0, ls1, ls2, ls3};
    #pragma unroll
    for (int r = 0; r < 4; r++) {
        float v = L[r];
        v += __shfl_xor(v, 1, 64);
        v += __shfl_xor(v, 2, 64);
        v += __shfl_xor(v, 4, 64);
        v += __shfl_xor(v, 8, 64);
        L[r] = v;
    }
    float4 ov;
    ov.x = o0[0] / L[0]; ov.y = o0[1] / L[1]; ov.z = o0[2] / L[2]; ov.w = o0[3] / L[3];
    *(float4*)(out + ((size_t)b * 128 + h * 16 + m) * NSP + q0 + quad * 4) = ov;
}

// ======= shuffle attn: gates + gn stats from raw per-channel stats =========
__global__ void sfold_kernel(const float* __restrict__ rawstats,
                             const float* __restrict__ cw1, const float* __restrict__ cw2,
                             float* __restrict__ gate0, float* __restrict__ gnstat) {
    int bg = blockIdx.x;
    int b = bg >> 2, g = bg & 3;
    __shared__ float sp[16], sh[4];
    int t = threadIdx.x;
    if (t < 16) sp[t] = rawstats[(b * 128 + g * 32 + t) * 2] / (float)NSP;
    __syncthreads();
    if (t < 4) {
        float a = 0.f;
        for (int j = 0; j < 16; j++) a = fmaf(cw1[t * 16 + j], sp[j], a);
        sh[t] = a / (1.f + __expf(-a));
    }
    __syncthreads();
    if (t < 16) {
        float a = 0.f;
        for (int r = 0; r < 4; r++) a = fmaf(cw2[t * 4 + r], sh[r], a);
        gate0[bg * 16 + t] = 1.f / (1.f + __expf(-a));
    }
    if (t < 2) {
        float S = 0.f, S2 = 0.f;
        for (int k = 0; k < 8; k++) {
            int c = g * 32 + 16 + t * 8 + k;
            S  += rawstats[(b * 128 + c) * 2];
            S2 += rawstats[(b * 128 + c) * 2 + 1];
        }
        float N = 8.f * NSP;
        float mean = S / N, var = S2 / N - mean * mean;
        gnstat[(bg * 2 + t) * 2]     = mean;
        gnstat[(bg * 2 + t) * 2 + 1] = rsqrtf(var + 1e-5f);
    }
}

// ======= shuffle attn: final gating + channel shuffle ----------------------
__global__ void sfinal_kernel(const float* __restrict__ X,
                              const float* __restrict__ gate0,
                              const float* __restrict__ stats,
                              const float* __restrict__ gng,
                              const float* __restrict__ gnb,
                              const float* __restrict__ sw,
                              float* __restrict__ out) {
    int bg = blockIdx.x;
    int b = bg >> 2, g = bg & 3;
    __shared__ float swl[256];
    for (int i = threadIdx.x; i < 256; i += 64) swl[i] = sw[i];
    __syncthreads();
    int n = blockIdx.y * 64 + threadIdx.x;
    const float* xb = X + (size_t)b * 128 * NSP;
    #pragma unroll
    for (int j = 0; j < 16; j++) {
        float v = xb[(size_t)(g * 32 + j) * NSP + n] * gate0[bg * 16 + j];
        int k = g * 16 + j;
        int cp = (k % 32) * 4 + (k / 32);
        out[((size_t)b * 128 + cp) * NSP + n] = v;
    }
    float sgn[16];
    #pragma unroll
    for (int j = 0; j < 16; j++) {
        int grp = j >> 3;
        float mean = stats[(bg * 2 + grp) * 2];
        float rstd = stats[(bg * 2 + grp) * 2 + 1];
        float xv = xb[(size_t)(g * 32 + 16 + j) * NSP + n];
        sgn[j] = (xv - mean) * rstd * gng[j] + gnb[j];
    }
    #pragma unroll
    for (int j = 0; j < 16; j++) {
        float a = 0.f;
        #pragma unroll
        for (int jp = 0; jp < 16; jp++) a = fmaf(swl[j * 16 + jp], sgn[jp], a);
        float v = (1.f / (1.f + __expf(-a))) * xb[(size_t)(g * 32 + 16 + j) * NSP + n];
        int k = 64 + g * 16 + j;
        int cp = (k % 32) * 4 + (k / 32);
        out[((size_t)b * 128 + cp) * NSP + n] = v;
    }
}

// ===========================================================================
extern "C" void kernel_launch(void* const* d_in, const int* in_sizes, int n_in,
                              void* d_out, int out_size, void* d_ws, size_t ws_size,
                              hipStream_t stream) {
    const float* x     = (const float*)d_in[0];
    const float* m1_ew = (const float*)d_in[1];
    const float* m1_g1 = (const float*)d_in[2];
    const float* m1_b1 = (const float*)d_in[3];
    const float* m1_dw = (const float*)d_in[4];
    const float* m1_g2 = (const float*)d_in[5];
    const float* m1_b2 = (const float*)d_in[6];
    const float* m1_sw1= (const float*)d_in[7];
    const float* m1_sb1= (const float*)d_in[8];
    const float* m1_sw2= (const float*)d_in[9];
    const float* m1_sb2= (const float*)d_in[10];
    const float* m1_pw = (const float*)d_in[11];
    const float* m1_g3 = (const float*)d_in[12];
    const float* m1_b3 = (const float*)d_in[13];
    const float* m2_ew = (const float*)d_in[14];
    const float* m2_g1 = (const float*)d_in[15];
    const float* m2_b1 = (const float*)d_in[16];
    const float* m2_dw = (const float*)d_in[17];
    const float* m2_g2 = (const float*)d_in[18];
    const float* m2_b2 = (const float*)d_in[19];
    const float* m2_sw1= (const float*)d_in[20];
    const float* m2_sb1= (const float*)d_in[21];
    const float* m2_sw2= (const float*)d_in[22];
    const float* m2_sb2= (const float*)d_in[23];
    const float* m2_pw = (const float*)d_in[24];
    const float* m2_g3 = (const float*)d_in[25];
    const float* m2_b3 = (const float*)d_in[26];
    const float* t_n1g = (const float*)d_in[27];
    const float* t_n1b = (const float*)d_in[28];
    const float* t_qkv = (const float*)d_in[29];
    const float* t_pw  = (const float*)d_in[30];
    const float* t_pb  = (const float*)d_in[31];
    const float* t_n2g = (const float*)d_in[32];
    const float* t_n2b = (const float*)d_in[33];
    const float* t_mw1 = (const float*)d_in[34];
    const float* t_mb1 = (const float*)d_in[35];
    const float* t_mw2 = (const float*)d_in[36];
    const float* t_mb2 = (const float*)d_in[37];
    const float* s_cw1 = (const float*)d_in[38];
    const float* s_cw2 = (const float*)d_in[39];
    const float* s_gng = (const float*)d_in[40];
    const float* s_gnb = (const float*)d_in[41];
    const float* s_sw  = (const float*)d_in[42];

    float* out = (float*)d_out;

    float* ws = (float*)d_ws;
    float* bufA   = ws;                                 // 2*512*NSP
    float* bufB   = bufA + (size_t)BB * 512 * NSP;      // 2*512*NSP
    float* bufX   = bufB + (size_t)BB * 512 * NSP;      // 2*128*NSP
    float* bufY   = bufX + (size_t)BB * 128 * NSP;      // 2*128*NSP
    float* bufQKV = bufY + (size_t)BB * 128 * NSP;      // 2*384*NSP
    float* small  = bufQKV + (size_t)BB * 384 * NSP;
    float* se_s    = small;           // 1024
    float* se_gate = small + 1024;    // 1024
    float* rawst   = small + 2048;    // 512
    float* scale1  = small + 2560;    // 256
    float* scale2  = small + 2816;    // 256
    float* biasb1  = small + 3072;    // 768
    float* biasb2  = small + 3840;    // 1024
    float* gate0   = small + 4864;    // 128
    float* gnstat  = small + 4992;    // 32

    dim3 blk(256);

    // ---------------- MBConv1: 64 -> 256 -> 128 ----------------
    mbk1_kernel<<<BB * 128, blk, 0, stream>>>(x, m1_ew, m1_g1, m1_b1, m1_dw, m1_g2, m1_b2, bufB, se_s, 64, 256);
    se_kernel<<<BB, blk, 0, stream>>>(se_s, m1_sw1, m1_sb1, m1_sw2, m1_sb2, se_gate, 256, 64);
    convfull_kernel<<<BB * 128, blk, 256 * 4, stream>>>(bufB, m1_pw, nullptr, se_gate, nullptr,
                                                        m1_g3, m1_b3, 1, bufX, nullptr, 256, 128);

    // ---------------- MBConv2: 128 -> 512 -> 128 (+res) ----------------
    mbk1_kernel<<<BB * 256, blk, 0, stream>>>(bufX, m2_ew, m2_g1, m2_b1, m2_dw, m2_g2, m2_b2, bufB, se_s, 128, 512);
    se_kernel<<<BB, blk, 0, stream>>>(se_s, m2_sw1, m2_sb1, m2_sw2, m2_sb2, se_gate, 512, 128);
    convfull_kernel<<<BB * 128, blk, 512 * 4, stream>>>(bufB, m2_pw, nullptr, se_gate, bufX,
                                                        m2_g3, m2_b3, 1, bufX, rawst, 512, 128);

    // ---------------- Transformer ----------------
    gfold_kernel<<<BB * 6, dim3(64), 0, stream>>>(rawst, t_n1g, t_n1b, t_qkv, nullptr, scale1, biasb1, 128, 384, 4);
    convsplit_kernel<<<dim3(BB * 96, 4), blk, 128 * 4 * 4, stream>>>(bufX, t_qkv, biasb1, scale1, bufQKV, 128, 384, 0);
    attn_mfma_kernel<<<dim3(16, 27), blk, 0, stream>>>(bufQKV, bufY);
    convfull_kernel<<<BB * 128, blk, 128 * 4, stream>>>(bufY, t_pw, t_pb, nullptr, bufX,
                                                        nullptr, nullptr, 0, bufX, rawst, 128, 128);
    gfold_kernel<<<BB * 8, dim3(64), 0, stream>>>(rawst, t_n2g, t_n2b, t_mw1, t_mb1, scale2, biasb2, 128, 512, 4);
    convsplit_kernel<<<dim3(BB * 128, 4), blk, 128 * 4 * 4, stream>>>(bufX, t_mw1, biasb2, scale2, bufA, 128, 512, 2);
    convfull_kernel<<<BB * 128, blk, 512 * 4, stream>>>(bufA, t_mw2, t_mb2, nullptr, bufX,
                                                        nullptr, nullptr, 0, bufX, rawst, 512, 128);

    // ---------------- Shuffle attention ----------------
    sfold_kernel<<<BB * 4, dim3(64), 0, stream>>>(rawst, s_cw1, s_cw2, gate0, gnstat);
    sfinal_kernel<<<dim3(BB * 4, 27), dim3(64), 0, stream>>>(bufX, gate0, gnstat, s_gng, s_gnb, s_sw, out);
}

// Round 4
// 499.687 us; speedup vs baseline: 4.0580x; 4.0580x over previous
//
#include <hip/hip_runtime.h>
#include <cmath>

#define NSP 1728   // 12*12*12
#define BB  2      // batch
#define SS  12

typedef __attribute__((ext_vector_type(8))) short short8;
typedef __attribute__((ext_vector_type(4))) short short4v;
typedef __attribute__((ext_vector_type(4))) float floatx4;

__device__ __forceinline__ short f2bf(float f) {
    unsigned u = __float_as_uint(f);
    u += 0x7fff + ((u >> 16) & 1);
    return (short)(u >> 16);
}
__device__ __forceinline__ short8 ld8(const short* p) {
    short4v a = *(const short4v*)p;
    short4v b = *(const short4v*)(p + 4);
    return __builtin_shufflevector(a, b, 0, 1, 2, 3, 4, 5, 6, 7);
}

// ---------------- block-wide dual reduction (sum, sumsq) -------------------
__device__ __forceinline__ void block_reduce2(float& s, float& s2) {
    __shared__ float red[8][2];
    __syncthreads();                 // protect red[] reuse across calls
    #pragma unroll
    for (int o = 32; o; o >>= 1) {
        s  += __shfl_down(s,  o, 64);
        s2 += __shfl_down(s2, o, 64);
    }
    int lane = threadIdx.x & 63, w = threadIdx.x >> 6;
    if (lane == 0) { red[w][0] = s; red[w][1] = s2; }
    __syncthreads();
    int nw = (blockDim.x + 63) >> 6;
    if (threadIdx.x == 0) {
        float a = 0.f, b = 0.f;
        for (int i = 0; i < nw; i++) { a += red[i][0]; b += red[i][1]; }
        red[0][0] = a; red[0][1] = b;
    }
    __syncthreads();
    s = red[0][0]; s2 = red[0][1];
}

// ======= Split-n 1x1 conv: 4 co per block, y n-tiles of 432 ================
// gate: [b,Cin] weight scale; biasc: [Cout]; biasb: [b,Cout]; resid: add;
// act 2 = exact GELU; stats_out: atomic raw (sum,sumsq) per (b,co).
__global__ __launch_bounds__(256) void convsplit_kernel(
        const float* __restrict__ in, const float* __restrict__ w,
        const float* __restrict__ biasc, const float* __restrict__ biasb,
        const float* __restrict__ gate, const float* resid,
        float* out, float* stats_out,
        int Cin, int Cout, int act) {
    int ncot = Cout >> 2;
    int b = blockIdx.x / ncot, ct = blockIdx.x % ncot;
    int co0 = ct << 2;
    extern __shared__ float wl[];         // [Cin][4]
    const float* wsrc = w + (size_t)co0 * Cin;
    const float* gp = gate ? gate + (size_t)b * Cin : nullptr;
    for (int idx = threadIdx.x; idx < Cin * 4; idx += 256) {
        int k = idx / Cin, ci = idx - k * Cin;
        float v = wsrc[idx];
        if (gp) v *= gp[ci];
        wl[ci * 4 + k] = v;
    }
    __syncthreads();
    bool act_thr = threadIdx.x < 216;
    int n0 = act_thr ? (blockIdx.y * 432 + threadIdx.x * 2) : 0;
    const float* ip = in + (size_t)b * Cin * NSP + n0;
    float ax0 = 0.f, ax1 = 0.f, ax2 = 0.f, ax3 = 0.f;
    float ay0 = 0.f, ay1 = 0.f, ay2 = 0.f, ay3 = 0.f;
    #pragma unroll 4
    for (int ci = 0; ci < Cin; ci++) {
        float2 iv = *(const float2*)(ip + (size_t)ci * NSP);
        float4 wv = *(const float4*)(wl + ci * 4);
        ax0 = fmaf(wv.x, iv.x, ax0); ay0 = fmaf(wv.x, iv.y, ay0);
        ax1 = fmaf(wv.y, iv.x, ax1); ay1 = fmaf(wv.y, iv.y, ay1);
        ax2 = fmaf(wv.z, iv.x, ax2); ay2 = fmaf(wv.z, iv.y, ay2);
        ax3 = fmaf(wv.w, iv.x, ax3); ay3 = fmaf(wv.w, iv.y, ay3);
    }
    float vx[4] = {ax0, ax1, ax2, ax3};
    float vy[4] = {ay0, ay1, ay2, ay3};
    #pragma unroll
    for (int k = 0; k < 4; k++) {
        int co = co0 + k;
        float bv = 0.f;
        if (biasc) bv += biasc[co];
        if (biasb) bv += biasb[b * Cout + co];
        vx[k] += bv; vy[k] += bv;
        if (act == 2) {
            vx[k] = 0.5f * vx[k] * (1.f + erff(vx[k] * 0.70710678118654752f));
            vy[k] = 0.5f * vy[k] * (1.f + erff(vy[k] * 0.70710678118654752f));
        }
        size_t oi = ((size_t)b * Cout + co) * NSP + n0;
        if (resid) { vx[k] += resid[oi]; vy[k] += resid[oi + 1]; }
        if (act_thr) {
            float2 o; o.x = vx[k]; o.y = vy[k];
            *(float2*)(out + oi) = o;
        }
    }
    if (stats_out) {
        #pragma unroll
        for (int k = 0; k < 4; k++) {
            float s  = act_thr ? (vx[k] + vy[k]) : 0.f;
            float s2 = act_thr ? (vx[k] * vx[k] + vy[k] * vy[k]) : 0.f;
            block_reduce2(s, s2);
            if (threadIdx.x == 0) {
                atomicAdd(&stats_out[(b * Cout + co0 + k) * 2], s);
                atomicAdd(&stats_out[(b * Cout + co0 + k) * 2 + 1], s2);
            }
        }
    }
}

// ======= fused InstanceNorm (+SiLU, +residual, +output raw stats) ==========
__global__ __launch_bounds__(256) void inorm_kernel(
        const float* __restrict__ in, float* out,
        const float* __restrict__ g, const float* __restrict__ b_,
        const float* resid, float* __restrict__ stats_out,
        int C, int do_silu) {
    int bc = blockIdx.x;
    int c  = bc % C;
    const float* p = in + (size_t)bc * NSP;
    float s = 0.f, s2 = 0.f;
    for (int n = threadIdx.x; n < NSP; n += 256) {
        float v = p[n]; s += v; s2 += v * v;
    }
    block_reduce2(s, s2);
    float mean = s / NSP;
    float var  = s2 / NSP - mean * mean;
    float rstd = rsqrtf(var + 1e-5f);
    float gc = g[c], bc2 = b_[c];
    float os = 0.f, os2 = 0.f;
    for (int n = threadIdx.x; n < NSP; n += 256) {
        float v = (p[n] - mean) * rstd * gc + bc2;
        if (do_silu) v = v / (1.f + __expf(-v));
        size_t oi = (size_t)bc * NSP + n;
        if (resid) v += resid[oi];
        out[oi] = v;
        os += v; os2 += v * v;
    }
    if (stats_out) {
        block_reduce2(os, os2);
        if (threadIdx.x == 0) {
            stats_out[bc * 2]     = os;
            stats_out[bc * 2 + 1] = os2;
        }
    }
}

// ======= IN+SiLU + depthwise 3x3x3 + IN+SiLU + SE-squeeze ==================
// grid b*C blocks of 256; input = raw expand-conv output.
__global__ __launch_bounds__(256) void indw_kernel(
        const float* __restrict__ in,
        const float* __restrict__ g1, const float* __restrict__ b1,
        const float* __restrict__ dw,
        const float* __restrict__ g2, const float* __restrict__ b2,
        float* __restrict__ out, float* __restrict__ se_s, int C) {
    int bc = blockIdx.x;
    int c  = bc % C;
    __shared__ float tile[NSP];
    __shared__ float wsh[27];
    const float* ip = in + (size_t)bc * NSP;
    float r[7];
    float s = 0.f, s2 = 0.f;
    #pragma unroll
    for (int i = 0; i < 7; i++) {
        int n = threadIdx.x + i * 256;
        if (n < NSP) { r[i] = ip[n]; s += r[i]; s2 += r[i] * r[i]; }
        else r[i] = 0.f;
    }
    if (threadIdx.x < 27) wsh[threadIdx.x] = dw[(size_t)c * 27 + threadIdx.x];
    block_reduce2(s, s2);
    float mean = s / NSP, var = s2 / NSP - (s / NSP) * (s / NSP);
    float rstd = rsqrtf(var + 1e-5f);
    float gc = g1[c], bc1 = b1[c];
    #pragma unroll
    for (int i = 0; i < 7; i++) {
        int n = threadIdx.x + i * 256;
        if (n < NSP) {
            float v = (r[i] - mean) * rstd * gc + bc1;
            tile[n] = v / (1.f + __expf(-v));
        }
    }
    __syncthreads();
    float d[7];
    #pragma unroll
    for (int i = 0; i < 7; i++) {
        int n = threadIdx.x + i * 256;
        d[i] = 0.f;
        if (n < NSP) {
            int z = n / 144, y = (n / 12) % 12, x = n % 12;
            #pragma unroll
            for (int dz = -1; dz <= 1; dz++) {
                int zz = z + dz; if (zz < 0 || zz >= SS) continue;
                #pragma unroll
                for (int dy = -1; dy <= 1; dy++) {
                    int yy = y + dy; if (yy < 0 || yy >= SS) continue;
                    #pragma unroll
                    for (int dx = -1; dx <= 1; dx++) {
                        int xx = x + dx; if (xx < 0 || xx >= SS) continue;
                        d[i] = fmaf(wsh[(dz + 1) * 9 + (dy + 1) * 3 + (dx + 1)],
                                    tile[(zz * 12 + yy) * 12 + xx], d[i]);
                    }
                }
            }
        }
    }
    s = 0.f; s2 = 0.f;
    #pragma unroll
    for (int i = 0; i < 7; i++) {
        int n = threadIdx.x + i * 256;
        if (n < NSP) { s += d[i]; s2 += d[i] * d[i]; }
    }
    block_reduce2(s, s2);
    mean = s / NSP; var = s2 / NSP - mean * mean;
    rstd = rsqrtf(var + 1e-5f);
    float gc2 = g2[c], bc2 = b2[c];
    float ssum = 0.f;
    float* op = out + (size_t)bc * NSP;
    #pragma unroll
    for (int i = 0; i < 7; i++) {
        int n = threadIdx.x + i * 256;
        if (n < NSP) {
            float v = (d[i] - mean) * rstd * gc2 + bc2;
            v = v / (1.f + __expf(-v));
            op[n] = v;
            ssum += v;
        }
    }
    float dummy = 0.f;
    block_reduce2(ssum, dummy);
    if (threadIdx.x == 0) se_s[bc] = ssum / NSP;
}

// ---------------- SE: fc1+silu, fc2+sigmoid --------------------------------
__global__ void se_kernel(const float* __restrict__ s,
                          const float* __restrict__ w1, const float* __restrict__ b1,
                          const float* __restrict__ w2, const float* __restrict__ b2,
                          float* __restrict__ gate, int C, int R) {
    __shared__ float sh_s[512];
    __shared__ float sh_h[128];
    int b = blockIdx.x;
    for (int c = threadIdx.x; c < C; c += blockDim.x) sh_s[c] = s[b * C + c];
    __syncthreads();
    for (int r = threadIdx.x; r < R; r += blockDim.x) {
        float a = b1[r];
        for (int c = 0; c < C; c++) a = fmaf(w1[(size_t)r * C + c], sh_s[c], a);
        sh_h[r] = a / (1.f + __expf(-a));
    }
    __syncthreads();
    for (int c = threadIdx.x; c < C; c += blockDim.x) {
        float a = b2[c];
        for (int r = 0; r < R; r++) a = fmaf(w2[(size_t)c * R + r], sh_h[r], a);
        gate[b * C + c] = 1.f / (1.f + __expf(-a));
    }
}

// ======= GroupNorm-fold ====================================================
__global__ void gfold_kernel(const float* __restrict__ rawstats,
                             const float* __restrict__ gamma, const float* __restrict__ beta,
                             const float* __restrict__ W, const float* __restrict__ bias_in,
                             float* __restrict__ scale, float* __restrict__ biasb,
                             int Cin, int Cout, int gs) {
    int nct = Cout / 64;
    int b = blockIdx.x / nct, ot = blockIdx.x % nct;
    __shared__ float sshift[128];
    for (int ci = threadIdx.x; ci < Cin; ci += 64) {
        int g0 = ci / gs;
        float S = 0.f, S2 = 0.f;
        for (int k = 0; k < gs; k++) {
            S  += rawstats[(b * Cin + g0 * gs + k) * 2];
            S2 += rawstats[(b * Cin + g0 * gs + k) * 2 + 1];
        }
        float N = gs * (float)NSP;
        float mean = S / N, var = S2 / N - mean * mean;
        float r = rsqrtf(var + 1e-5f);
        float sc = r * gamma[ci];
        sshift[ci] = beta[ci] - mean * sc;
        if (ot == 0) scale[b * Cin + ci] = sc;
    }
    __syncthreads();
    int o = ot * 64 + threadIdx.x;
    float acc = bias_in ? bias_in[o] : 0.f;
    for (int ci = 0; ci < Cin; ci++)
        acc = fmaf(W[(size_t)o * Cin + ci], sshift[ci], acc);
    biasb[b * Cout + o] = acc;
}

// ======= MFMA flash attention (validated R3) ===============================
#define KTP 20
#define VTP 196
#define PTP 36
__global__ __launch_bounds__(256) void attn_mfma_kernel(const float* __restrict__ qkv,
                                                        float* __restrict__ out) {
    __shared__ __align__(16) short kt[192 * KTP];
    __shared__ __align__(16) short vt[16 * VTP];
    __shared__ __align__(16) short pt[4][16 * PTP];
    int bh = blockIdx.x;
    int b = bh >> 3, h = bh & 7;
    const float* base = qkv + (size_t)b * 384 * NSP;
    const float* qp = base + (size_t)(h * 16) * NSP;
    const float* kp = base + (size_t)(128 + h * 16) * NSP;
    const float* vp = base + (size_t)(256 + h * 16) * NSP;
    int wave = threadIdx.x >> 6, lane = threadIdx.x & 63;
    int m = lane & 15, quad = lane >> 4;
    int q0 = (blockIdx.y * 4 + wave) * 16;
    short* ptw = pt[wave];
    short8 qa;
    #pragma unroll
    for (int i = 0; i < 8; i++) qa[i] = 0;
    if (quad < 2) {
        #pragma unroll
        for (int i = 0; i < 8; i++) {
            int d = quad * 8 + i;
            qa[i] = f2bf(qp[(size_t)d * NSP + q0 + m] * 0.25f);
        }
    }
    floatx4 o0 = {0.f, 0.f, 0.f, 0.f};
    float ls0 = 0.f, ls1 = 0.f, ls2 = 0.f, ls3 = 0.f;
    for (int jc = 0; jc < 9; jc++) {
        int j0 = jc * 192;
        __syncthreads();
        for (int idx = threadIdx.x; idx < 3072; idx += 256) {
            int d = idx / 192, j = idx - d * 192;
            kt[j * KTP + d] = f2bf(kp[(size_t)d * NSP + j0 + j]);
            vt[d * VTP + j] = f2bf(vp[(size_t)d * NSP + j0 + j]);
        }
        __syncthreads();
        for (int s = 0; s < 6; s++) {
            int jl = s * 32;
            short8 bk0, bk1;
            #pragma unroll
            for (int i = 0; i < 8; i++) { bk0[i] = 0; bk1[i] = 0; }
            if (quad < 2) {
                bk0 = ld8(kt + (jl + m) * KTP + quad * 8);
                bk1 = ld8(kt + (jl + 16 + m) * KTP + quad * 8);
            }
            floatx4 s0 = {0.f, 0.f, 0.f, 0.f}, s1 = {0.f, 0.f, 0.f, 0.f};
            s0 = __builtin_amdgcn_mfma_f32_16x16x32_bf16(qa, bk0, s0, 0, 0, 0);
            s1 = __builtin_amdgcn_mfma_f32_16x16x32_bf16(qa, bk1, s1, 0, 0, 0);
            float p00 = __expf(s0[0]), p01 = __expf(s0[1]), p02 = __expf(s0[2]), p03 = __expf(s0[3]);
            float p10 = __expf(s1[0]), p11 = __expf(s1[1]), p12 = __expf(s1[2]), p13 = __expf(s1[3]);
            ls0 += p00 + p10; ls1 += p01 + p11; ls2 += p02 + p12; ls3 += p03 + p13;
            int rw = quad * 4;
            ptw[(rw + 0) * PTP + m] = f2bf(p00);
            ptw[(rw + 1) * PTP + m] = f2bf(p01);
            ptw[(rw + 2) * PTP + m] = f2bf(p02);
            ptw[(rw + 3) * PTP + m] = f2bf(p03);
            ptw[(rw + 0) * PTP + 16 + m] = f2bf(p10);
            ptw[(rw + 1) * PTP + 16 + m] = f2bf(p11);
            ptw[(rw + 2) * PTP + 16 + m] = f2bf(p12);
            ptw[(rw + 3) * PTP + 16 + m] = f2bf(p13);
            short8 pa = ld8(ptw + m * PTP + quad * 8);
            short8 vb = ld8(vt + m * VTP + jl + quad * 8);
            o0 = __builtin_amdgcn_mfma_f32_16x16x32_bf16(pa, vb, o0, 0, 0, 0);
        }
    }
    float L[4] = {ls0, ls1, ls2, ls3};
    #pragma unroll
    for (int r = 0; r < 4; r++) {
        float v = L[r];
        v += __shfl_xor(v, 1, 64);
        v += __shfl_xor(v, 2, 64);
        v += __shfl_xor(v, 4, 64);
        v += __shfl_xor(v, 8, 64);
        L[r] = v;
    }
    float4 ov;
    ov.x = o0[0] / L[0]; ov.y = o0[1] / L[1]; ov.z = o0[2] / L[2]; ov.w = o0[3] / L[3];
    *(float4*)(out + ((size_t)b * 128 + h * 16 + m) * NSP + q0 + quad * 4) = ov;
}

// ======= shuffle attn: gates + gn stats from raw per-channel stats =========
__global__ void sfold_kernel(const float* __restrict__ rawstats,
                             const float* __restrict__ cw1, const float* __restrict__ cw2,
                             float* __restrict__ gate0, float* __restrict__ gnstat) {
    int bg = blockIdx.x;
    int b = bg >> 2, g = bg & 3;
    __shared__ float sp[16], sh[4];
    int t = threadIdx.x;
    if (t < 16) sp[t] = rawstats[(b * 128 + g * 32 + t) * 2] / (float)NSP;
    __syncthreads();
    if (t < 4) {
        float a = 0.f;
        for (int j = 0; j < 16; j++) a = fmaf(cw1[t * 16 + j], sp[j], a);
        sh[t] = a / (1.f + __expf(-a));
    }
    __syncthreads();
    if (t < 16) {
        float a = 0.f;
        for (int r = 0; r < 4; r++) a = fmaf(cw2[t * 4 + r], sh[r], a);
        gate0[bg * 16 + t] = 1.f / (1.f + __expf(-a));
    }
    if (t < 2) {
        float S = 0.f, S2 = 0.f;
        for (int k = 0; k < 8; k++) {
            int c = g * 32 + 16 + t * 8 + k;
            S  += rawstats[(b * 128 + c) * 2];
            S2 += rawstats[(b * 128 + c) * 2 + 1];
        }
        float N = 8.f * NSP;
        float mean = S / N, var = S2 / N - mean * mean;
        gnstat[(bg * 2 + t) * 2]     = mean;
        gnstat[(bg * 2 + t) * 2 + 1] = rsqrtf(var + 1e-5f);
    }
}

// ======= shuffle attn: final gating + channel shuffle ----------------------
__global__ void sfinal_kernel(const float* __restrict__ X,
                              const float* __restrict__ gate0,
                              const float* __restrict__ stats,
                              const float* __restrict__ gng,
                              const float* __restrict__ gnb,
                              const float* __restrict__ sw,
                              float* __restrict__ out) {
    int bg = blockIdx.x;
    int b = bg >> 2, g = bg & 3;
    __shared__ float swl[256];
    for (int i = threadIdx.x; i < 256; i += 64) swl[i] = sw[i];
    __syncthreads();
    int n = blockIdx.y * 64 + threadIdx.x;
    const float* xb = X + (size_t)b * 128 * NSP;
    #pragma unroll
    for (int j = 0; j < 16; j++) {
        float v = xb[(size_t)(g * 32 + j) * NSP + n] * gate0[bg * 16 + j];
        int k = g * 16 + j;
        int cp = (k % 32) * 4 + (k / 32);
        out[((size_t)b * 128 + cp) * NSP + n] = v;
    }
    float sgn[16];
    #pragma unroll
    for (int j = 0; j < 16; j++) {
        int grp = j >> 3;
        float mean = stats[(bg * 2 + grp) * 2];
        float rstd = stats[(bg * 2 + grp) * 2 + 1];
        float xv = xb[(size_t)(g * 32 + 16 + j) * NSP + n];
        sgn[j] = (xv - mean) * rstd * gng[j] + gnb[j];
    }
    #pragma unroll
    for (int j = 0; j < 16; j++) {
        float a = 0.f;
        #pragma unroll
        for (int jp = 0; jp < 16; jp++) a = fmaf(swl[j * 16 + jp], sgn[jp], a);
        float v = (1.f / (1.f + __expf(-a))) * xb[(size_t)(g * 32 + 16 + j) * NSP + n];
        int k = 64 + g * 16 + j;
        int cp = (k % 32) * 4 + (k / 32);
        out[((size_t)b * 128 + cp) * NSP + n] = v;
    }
}

// ===========================================================================
extern "C" void kernel_launch(void* const* d_in, const int* in_sizes, int n_in,
                              void* d_out, int out_size, void* d_ws, size_t ws_size,
                              hipStream_t stream) {
    const float* x     = (const float*)d_in[0];
    const float* m1_ew = (const float*)d_in[1];
    const float* m1_g1 = (const float*)d_in[2];
    const float* m1_b1 = (const float*)d_in[3];
    const float* m1_dw = (const float*)d_in[4];
    const float* m1_g2 = (const float*)d_in[5];
    const float* m1_b2 = (const float*)d_in[6];
    const float* m1_sw1= (const float*)d_in[7];
    const float* m1_sb1= (const float*)d_in[8];
    const float* m1_sw2= (const float*)d_in[9];
    const float* m1_sb2= (const float*)d_in[10];
    const float* m1_pw = (const float*)d_in[11];
    const float* m1_g3 = (const float*)d_in[12];
    const float* m1_b3 = (const float*)d_in[13];
    const float* m2_ew = (const float*)d_in[14];
    const float* m2_g1 = (const float*)d_in[15];
    const float* m2_b1 = (const float*)d_in[16];
    const float* m2_dw = (const float*)d_in[17];
    const float* m2_g2 = (const float*)d_in[18];
    const float* m2_b2 = (const float*)d_in[19];
    const float* m2_sw1= (const float*)d_in[20];
    const float* m2_sb1= (const float*)d_in[21];
    const float* m2_sw2= (const float*)d_in[22];
    const float* m2_sb2= (const float*)d_in[23];
    const float* m2_pw = (const float*)d_in[24];
    const float* m2_g3 = (const float*)d_in[25];
    const float* m2_b3 = (const float*)d_in[26];
    const float* t_n1g = (const float*)d_in[27];
    const float* t_n1b = (const float*)d_in[28];
    const float* t_qkv = (const float*)d_in[29];
    const float* t_pw  = (const float*)d_in[30];
    const float* t_pb  = (const float*)d_in[31];
    const float* t_n2g = (const float*)d_in[32];
    const float* t_n2b = (const float*)d_in[33];
    const float* t_mw1 = (const float*)d_in[34];
    const float* t_mb1 = (const float*)d_in[35];
    const float* t_mw2 = (const float*)d_in[36];
    const float* t_mb2 = (const float*)d_in[37];
    const float* s_cw1 = (const float*)d_in[38];
    const float* s_cw2 = (const float*)d_in[39];
    const float* s_gng = (const float*)d_in[40];
    const float* s_gnb = (const float*)d_in[41];
    const float* s_sw  = (const float*)d_in[42];

    float* out = (float*)d_out;

    float* ws = (float*)d_ws;
    float* bufA   = ws;                                 // 2*512*NSP
    float* bufB   = bufA + (size_t)BB * 512 * NSP;      // 2*512*NSP
    float* bufX   = bufB + (size_t)BB * 512 * NSP;      // 2*128*NSP
    float* bufY   = bufX + (size_t)BB * 128 * NSP;      // 2*128*NSP
    float* bufQKV = bufY + (size_t)BB * 128 * NSP;      // 2*384*NSP
    float* small  = bufQKV + (size_t)BB * 384 * NSP;
    float* se_s    = small;           // 1024
    float* se_gate = small + 1024;    // 1024
    float* rawst   = small + 2048;    // 512  (mbconv2 output stats)
    float* rawst2  = small + 2560;    // 512  (attn-proj output stats, atomic)
    float* rawst3  = small + 3072;    // 512  (mlp2 output stats, atomic)
    float* scale1  = small + 3584;    // 256
    float* scale2  = small + 3840;    // 256
    float* biasb1  = small + 4096;    // 768
    float* biasb2  = small + 4864;    // 1024
    float* gate0   = small + 5888;    // 128
    float* gnstat  = small + 6016;    // 32

    dim3 blk(256);

    // zero the atomic-accumulated stats buffers (rawst2 + rawst3, contiguous)
    hipMemsetAsync(rawst2, 0, 1024 * sizeof(float), stream);

    // ---------------- MBConv1: 64 -> 256 -> 128 ----------------
    convsplit_kernel<<<dim3(BB * 64, 4), blk, 64 * 16, stream>>>(
        x, m1_ew, nullptr, nullptr, nullptr, nullptr, bufA, nullptr, 64, 256, 0);
    indw_kernel<<<BB * 256, blk, 0, stream>>>(bufA, m1_g1, m1_b1, m1_dw, m1_g2, m1_b2, bufB, se_s, 256);
    se_kernel<<<BB, blk, 0, stream>>>(se_s, m1_sw1, m1_sb1, m1_sw2, m1_sb2, se_gate, 256, 64);
    convsplit_kernel<<<dim3(BB * 32, 4), blk, 256 * 16, stream>>>(
        bufB, m1_pw, nullptr, nullptr, se_gate, nullptr, bufY, nullptr, 256, 128, 0);
    inorm_kernel<<<BB * 128, blk, 0, stream>>>(bufY, bufX, m1_g3, m1_b3, nullptr, nullptr, 128, 0);

    // ---------------- MBConv2: 128 -> 512 -> 128 (+res) ----------------
    convsplit_kernel<<<dim3(BB * 128, 4), blk, 128 * 16, stream>>>(
        bufX, m2_ew, nullptr, nullptr, nullptr, nullptr, bufA, nullptr, 128, 512, 0);
    indw_kernel<<<BB * 512, blk, 0, stream>>>(bufA, m2_g1, m2_b1, m2_dw, m2_g2, m2_b2, bufB, se_s, 512);
    se_kernel<<<BB, blk, 0, stream>>>(se_s, m2_sw1, m2_sb1, m2_sw2, m2_sb2, se_gate, 512, 128);
    convsplit_kernel<<<dim3(BB * 32, 4), blk, 512 * 16, stream>>>(
        bufB, m2_pw, nullptr, nullptr, se_gate, nullptr, bufY, nullptr, 512, 128, 0);
    inorm_kernel<<<BB * 128, blk, 0, stream>>>(bufY, bufX, m2_g3, m2_b3, bufX, rawst, 128, 0);

    // ---------------- Transformer ----------------
    gfold_kernel<<<BB * 6, dim3(64), 0, stream>>>(rawst, t_n1g, t_n1b, t_qkv, nullptr, scale1, biasb1, 128, 384, 4);
    convsplit_kernel<<<dim3(BB * 96, 4), blk, 128 * 16, stream>>>(
        bufX, t_qkv, nullptr, biasb1, scale1, nullptr, bufQKV, nullptr, 128, 384, 0);
    attn_mfma_kernel<<<dim3(16, 27), blk, 0, stream>>>(bufQKV, bufY);
    convsplit_kernel<<<dim3(BB * 32, 4), blk, 128 * 16, stream>>>(
        bufY, t_pw, t_pb, nullptr, nullptr, bufX, bufX, rawst2, 128, 128, 0);
    gfold_kernel<<<BB * 8, dim3(64), 0, stream>>>(rawst2, t_n2g, t_n2b, t_mw1, t_mb1, scale2, biasb2, 128, 512, 4);
    convsplit_kernel<<<dim3(BB * 128, 4), blk, 128 * 16, stream>>>(
        bufX, t_mw1, nullptr, biasb2, scale2, nullptr, bufA, nullptr, 128, 512, 2);
    convsplit_kernel<<<dim3(BB * 32, 4), blk, 512 * 16, stream>>>(
        bufA, t_mw2, t_mb2, nullptr, nullptr, bufX, bufX, rawst3, 512, 128, 0);

    // ---------------- Shuffle attention ----------------
    sfold_kernel<<<BB * 4, dim3(64), 0, stream>>>(rawst3, s_cw1, s_cw2, gate0, gnstat);
    sfinal_kernel<<<dim3(BB * 4, 27), dim3(64), 0, stream>>>(bufX, gate0, gnstat, s_gng, s_gnb, s_sw, out);
}

// Round 5
// 412.818 us; speedup vs baseline: 4.9119x; 1.2104x over previous
//
#include <hip/hip_runtime.h>
#include <cmath>

#define NSP 1728   // 12*12*12
#define BB  2      // batch
#define SS  12

typedef __attribute__((ext_vector_type(8))) short short8;
typedef __attribute__((ext_vector_type(4))) short short4v;
typedef __attribute__((ext_vector_type(4))) float floatx4;

__device__ __forceinline__ short f2bf(float f) {
    unsigned u = __float_as_uint(f);
    u += 0x7fff + ((u >> 16) & 1);
    return (short)(u >> 16);
}
__device__ __forceinline__ unsigned pack2bf(float a, float b) {
    unsigned ua = __float_as_uint(a); ua += 0x7fff + ((ua >> 16) & 1);
    unsigned ub = __float_as_uint(b); ub += 0x7fff + ((ub >> 16) & 1);
    return (ua >> 16) | (ub & 0xffff0000u);
}
__device__ __forceinline__ short8 ld8(const short* p) {
    short4v a = *(const short4v*)p;
    short4v b = *(const short4v*)(p + 4);
    return __builtin_shufflevector(a, b, 0, 1, 2, 3, 4, 5, 6, 7);
}

// ---------------- block-wide dual reduction (sum, sumsq) -------------------
__device__ __forceinline__ void block_reduce2(float& s, float& s2) {
    __shared__ float red[8][2];
    __syncthreads();                 // protect red[] reuse across calls
    #pragma unroll
    for (int o = 32; o; o >>= 1) {
        s  += __shfl_down(s,  o, 64);
        s2 += __shfl_down(s2, o, 64);
    }
    int lane = threadIdx.x & 63, w = threadIdx.x >> 6;
    if (lane == 0) { red[w][0] = s; red[w][1] = s2; }
    __syncthreads();
    int nw = (blockDim.x + 63) >> 6;
    if (threadIdx.x == 0) {
        float a = 0.f, b = 0.f;
        for (int i = 0; i < nw; i++) { a += red[i][0]; b += red[i][1]; }
        red[0][0] = a; red[0][1] = b;
    }
    __syncthreads();
    s = red[0][0]; s2 = red[0][1];
}

// ======= 1x1 conv: 4 co / block, 1 n / thread, y n-tiles of 216, z k-split =
// When gridDim.z > 1: writes raw partials at out + z*BB*Cout*NSP, skips post.
// Else: biasc[Cout] + biasb[b,Cout] + act(2=GELU) + resid + atomic raw stats.
__global__ __launch_bounds__(256) void convn1_kernel(
        const float* __restrict__ in, const float* __restrict__ w,
        const float* __restrict__ biasc, const float* __restrict__ biasb,
        const float* __restrict__ gate, const float* resid,
        float* out, float* stats_out,
        int Cin, int Cout, int act) {
    int ncot = Cout >> 2;
    int b = blockIdx.x / ncot, ct = blockIdx.x % ncot;
    int co0 = ct << 2;
    int ksplit = gridDim.z;
    int csz = Cin / ksplit;
    int c0 = blockIdx.z * csz;
    bool partial = (ksplit > 1);
    extern __shared__ float wl[];         // [csz][4]
    const float* wsrc = w + (size_t)co0 * Cin + c0;
    const float* gp = gate ? gate + (size_t)b * Cin + c0 : nullptr;
    for (int idx = threadIdx.x; idx < csz * 4; idx += 256) {
        int k = idx / csz, ci = idx - k * csz;
        float v = wsrc[(size_t)k * Cin + ci];
        if (gp) v *= gp[ci];
        wl[ci * 4 + k] = v;
    }
    __syncthreads();
    bool act_thr = threadIdx.x < 216;
    int n0 = act_thr ? (blockIdx.y * 216 + threadIdx.x) : 0;
    const float* ip = in + ((size_t)b * Cin + c0) * NSP + n0;
    float a0 = 0.f, a1 = 0.f, a2 = 0.f, a3 = 0.f;
    #pragma unroll 8
    for (int ci = 0; ci < csz; ci++) {
        float iv = ip[(size_t)ci * NSP];
        float4 wv = *(const float4*)(wl + ci * 4);
        a0 = fmaf(wv.x, iv, a0);
        a1 = fmaf(wv.y, iv, a1);
        a2 = fmaf(wv.z, iv, a2);
        a3 = fmaf(wv.w, iv, a3);
    }
    float vv[4] = {a0, a1, a2, a3};
    if (partial) {
        float* op = out + (size_t)blockIdx.z * BB * Cout * NSP;
        if (act_thr) {
            #pragma unroll
            for (int k = 0; k < 4; k++)
                op[((size_t)b * Cout + co0 + k) * NSP + n0] = vv[k];
        }
        return;
    }
    #pragma unroll
    for (int k = 0; k < 4; k++) {
        int co = co0 + k;
        float bv = 0.f;
        if (biasc) bv += biasc[co];
        if (biasb) bv += biasb[b * Cout + co];
        vv[k] += bv;
        if (act == 2)
            vv[k] = 0.5f * vv[k] * (1.f + erff(vv[k] * 0.70710678118654752f));
        size_t oi = ((size_t)b * Cout + co) * NSP + n0;
        if (resid) vv[k] += resid[oi];
        if (act_thr) out[oi] = vv[k];
    }
    if (stats_out) {
        #pragma unroll
        for (int k = 0; k < 4; k++) {
            float s  = act_thr ? vv[k] : 0.f;
            float s2 = act_thr ? vv[k] * vv[k] : 0.f;
            block_reduce2(s, s2);
            if (threadIdx.x == 0) {
                atomicAdd(&stats_out[(b * Cout + co0 + k) * 2], s);
                atomicAdd(&stats_out[(b * Cout + co0 + k) * 2 + 1], s2);
            }
        }
    }
}

// ======= post2: out = [IN](p0+p1+biasc) [+resid], optional raw stats =======
__global__ __launch_bounds__(256) void post2_kernel(
        const float* __restrict__ p0, const float* __restrict__ p1,
        const float* __restrict__ biasc,
        const float* __restrict__ ng, const float* __restrict__ nb, int do_norm,
        const float* resid, float* out, float* __restrict__ stats_out, int C) {
    int bc = blockIdx.x;
    int c  = bc % C;
    const float* a = p0 + (size_t)bc * NSP;
    const float* d = p1 + (size_t)bc * NSP;
    float bv = biasc ? biasc[c] : 0.f;
    float r[7];
    float s = 0.f, s2 = 0.f;
    #pragma unroll
    for (int i = 0; i < 7; i++) {
        int n = threadIdx.x + i * 256;
        if (n < NSP) { r[i] = a[n] + d[n] + bv; s += r[i]; s2 += r[i] * r[i]; }
        else r[i] = 0.f;
    }
    float mean = 0.f, rstd = 1.f, gc = 1.f, bc2 = 0.f;
    if (do_norm) {
        block_reduce2(s, s2);
        mean = s / NSP;
        float var = s2 / NSP - mean * mean;
        rstd = rsqrtf(var + 1e-5f);
        gc = ng[c]; bc2 = nb[c];
    }
    float os = 0.f, os2 = 0.f;
    #pragma unroll
    for (int i = 0; i < 7; i++) {
        int n = threadIdx.x + i * 256;
        if (n < NSP) {
            float v = do_norm ? (r[i] - mean) * rstd * gc + bc2 : r[i];
            size_t oi = (size_t)bc * NSP + n;
            if (resid) v += resid[oi];
            out[oi] = v;
            os += v; os2 += v * v;
        }
    }
    if (stats_out) {
        block_reduce2(os, os2);
        if (threadIdx.x == 0) {
            stats_out[bc * 2]     = os;
            stats_out[bc * 2 + 1] = os2;
        }
    }
}

// ======= IN+SiLU + depthwise 3x3x3 + IN+SiLU + SE-squeeze ==================
__global__ __launch_bounds__(256) void indw_kernel(
        const float* __restrict__ in,
        const float* __restrict__ g1, const float* __restrict__ b1,
        const float* __restrict__ dw,
        const float* __restrict__ g2, const float* __restrict__ b2,
        float* __restrict__ out, float* __restrict__ se_s, int C) {
    int bc = blockIdx.x;
    int c  = bc % C;
    __shared__ float tile[NSP];
    __shared__ float wsh[27];
    const float* ip = in + (size_t)bc * NSP;
    float r[7];
    float s = 0.f, s2 = 0.f;
    #pragma unroll
    for (int i = 0; i < 7; i++) {
        int n = threadIdx.x + i * 256;
        if (n < NSP) { r[i] = ip[n]; s += r[i]; s2 += r[i] * r[i]; }
        else r[i] = 0.f;
    }
    if (threadIdx.x < 27) wsh[threadIdx.x] = dw[(size_t)c * 27 + threadIdx.x];
    block_reduce2(s, s2);
    float mean = s / NSP, var = s2 / NSP - (s / NSP) * (s / NSP);
    float rstd = rsqrtf(var + 1e-5f);
    float gc = g1[c], bc1 = b1[c];
    #pragma unroll
    for (int i = 0; i < 7; i++) {
        int n = threadIdx.x + i * 256;
        if (n < NSP) {
            float v = (r[i] - mean) * rstd * gc + bc1;
            tile[n] = v / (1.f + __expf(-v));
        }
    }
    __syncthreads();
    float d[7];
    #pragma unroll
    for (int i = 0; i < 7; i++) {
        int n = threadIdx.x + i * 256;
        d[i] = 0.f;
        if (n < NSP) {
            int z = n / 144, y = (n / 12) % 12, x = n % 12;
            #pragma unroll
            for (int dz = -1; dz <= 1; dz++) {
                int zz = z + dz; if (zz < 0 || zz >= SS) continue;
                #pragma unroll
                for (int dy = -1; dy <= 1; dy++) {
                    int yy = y + dy; if (yy < 0 || yy >= SS) continue;
                    #pragma unroll
                    for (int dx = -1; dx <= 1; dx++) {
                        int xx = x + dx; if (xx < 0 || xx >= SS) continue;
                        d[i] = fmaf(wsh[(dz + 1) * 9 + (dy + 1) * 3 + (dx + 1)],
                                    tile[(zz * 12 + yy) * 12 + xx], d[i]);
                    }
                }
            }
        }
    }
    s = 0.f; s2 = 0.f;
    #pragma unroll
    for (int i = 0; i < 7; i++) {
        int n = threadIdx.x + i * 256;
        if (n < NSP) { s += d[i]; s2 += d[i] * d[i]; }
    }
    block_reduce2(s, s2);
    mean = s / NSP; var = s2 / NSP - mean * mean;
    rstd = rsqrtf(var + 1e-5f);
    float gc2 = g2[c], bc2 = b2[c];
    float ssum = 0.f;
    float* op = out + (size_t)bc * NSP;
    #pragma unroll
    for (int i = 0; i < 7; i++) {
        int n = threadIdx.x + i * 256;
        if (n < NSP) {
            float v = (d[i] - mean) * rstd * gc2 + bc2;
            v = v / (1.f + __expf(-v));
            op[n] = v;
            ssum += v;
        }
    }
    float dummy = 0.f;
    block_reduce2(ssum, dummy);
    if (threadIdx.x == 0) se_s[bc] = ssum / NSP;
}

// ---------------- SE: fc1+silu, fc2+sigmoid --------------------------------
__global__ void se_kernel(const float* __restrict__ s,
                          const float* __restrict__ w1, const float* __restrict__ b1,
                          const float* __restrict__ w2, const float* __restrict__ b2,
                          float* __restrict__ gate, int C, int R) {
    __shared__ float sh_s[512];
    __shared__ float sh_h[128];
    int b = blockIdx.x;
    for (int c = threadIdx.x; c < C; c += blockDim.x) sh_s[c] = s[b * C + c];
    __syncthreads();
    for (int r = threadIdx.x; r < R; r += blockDim.x) {
        float a = b1[r];
        for (int c = 0; c < C; c++) a = fmaf(w1[(size_t)r * C + c], sh_s[c], a);
        sh_h[r] = a / (1.f + __expf(-a));
    }
    __syncthreads();
    for (int c = threadIdx.x; c < C; c += blockDim.x) {
        float a = b2[c];
        for (int r = 0; r < R; r++) a = fmaf(w2[(size_t)c * R + r], sh_h[r], a);
        gate[b * C + c] = 1.f / (1.f + __expf(-a));
    }
}

// ======= GroupNorm-fold ====================================================
__global__ void gfold_kernel(const float* __restrict__ rawstats,
                             const float* __restrict__ gamma, const float* __restrict__ beta,
                             const float* __restrict__ W, const float* __restrict__ bias_in,
                             float* __restrict__ scale, float* __restrict__ biasb,
                             int Cin, int Cout, int gs) {
    int nct = Cout / 64;
    int b = blockIdx.x / nct, ot = blockIdx.x % nct;
    __shared__ float sshift[128];
    for (int ci = threadIdx.x; ci < Cin; ci += 64) {
        int g0 = ci / gs;
        float S = 0.f, S2 = 0.f;
        for (int k = 0; k < gs; k++) {
            S  += rawstats[(b * Cin + g0 * gs + k) * 2];
            S2 += rawstats[(b * Cin + g0 * gs + k) * 2 + 1];
        }
        float N = gs * (float)NSP;
        float mean = S / N, var = S2 / N - mean * mean;
        float r = rsqrtf(var + 1e-5f);
        float sc = r * gamma[ci];
        sshift[ci] = beta[ci] - mean * sc;
        if (ot == 0) scale[b * Cin + ci] = sc;
    }
    __syncthreads();
    int o = ot * 64 + threadIdx.x;
    float acc = bias_in ? bias_in[o] : 0.f;
    for (int ci = 0; ci < Cin; ci++)
        acc = fmaf(W[(size_t)o * Cin + ci], sshift[ci], acc);
    biasb[b * Cout + o] = acc;
}

// ======= MFMA flash attention, j-split 6, S^T formulation ==================
// grid (16 bh, 27 qtiles, 6 jsplit), block 256 = 4 waves; wave owns 16 q.
// S^T = K·Q^T  (C layout: per-lane 4 contiguous j for q=lane&15 -> packed P
// writes); PV as O^T = V^T·P^T.  exp2 with log2e folded into Q scale.
#define AKT 20
#define AVT 296
#define APT 36
#define JCH 288
__global__ __launch_bounds__(256) void attn_split_kernel(const float* __restrict__ qkv,
                                                         float* __restrict__ po,
                                                         float* __restrict__ pl) {
    __shared__ __align__(16) short kt[JCH * AKT];   // [j][d]
    __shared__ __align__(16) short vt[16 * AVT];    // [d][j]
    __shared__ __align__(16) short pt[4][16 * APT]; // per wave [q][j]
    int bh = blockIdx.x;
    int b = bh >> 3, h = bh & 7;
    int js = blockIdx.z;
    int j0 = js * JCH;
    const float* base = qkv + (size_t)b * 384 * NSP;
    const float* qp = base + (size_t)(h * 16) * NSP;
    const float* kp = base + (size_t)(128 + h * 16) * NSP;
    const float* vp = base + (size_t)(256 + h * 16) * NSP;
    for (int t = threadIdx.x; t < 16 * 144; t += 256) {
        int d = t / 144, j = (t - d * 144) * 2;
        float2 kv2 = *(const float2*)(kp + (size_t)d * NSP + j0 + j);
        float2 vv2 = *(const float2*)(vp + (size_t)d * NSP + j0 + j);
        kt[j * AKT + d]       = f2bf(kv2.x);
        kt[(j + 1) * AKT + d] = f2bf(kv2.y);
        *(unsigned*)(vt + d * AVT + j) = pack2bf(vv2.x, vv2.y);
    }
    int wave = threadIdx.x >> 6, lane = threadIdx.x & 63;
    int m = lane & 15, quad = lane >> 4;
    int q0 = (blockIdx.y * 4 + wave) * 16;
    short* ptw = pt[wave];
    short8 qa;
    #pragma unroll
    for (int i = 0; i < 8; i++) qa[i] = 0;
    if (quad < 2) {
        #pragma unroll
        for (int i = 0; i < 8; i++) {
            int d = quad * 8 + i;
            // 0.25 * log2(e)
            qa[i] = f2bf(qp[(size_t)d * NSP + q0 + m] * 0.36067376022224085f);
        }
    }
    __syncthreads();
    floatx4 o = {0.f, 0.f, 0.f, 0.f};
    float ls = 0.f;
    for (int s = 0; s < 9; s++) {
        int jl = s * 32;
        short8 ak0, ak1;
        #pragma unroll
        for (int i = 0; i < 8; i++) { ak0[i] = 0; ak1[i] = 0; }
        if (quad < 2) {
            ak0 = ld8(kt + (jl + m) * AKT + quad * 8);
            ak1 = ld8(kt + (jl + 16 + m) * AKT + quad * 8);
        }
        floatx4 s0 = {0.f, 0.f, 0.f, 0.f}, s1 = {0.f, 0.f, 0.f, 0.f};
        s0 = __builtin_amdgcn_mfma_f32_16x16x32_bf16(ak0, qa, s0, 0, 0, 0);
        s1 = __builtin_amdgcn_mfma_f32_16x16x32_bf16(ak1, qa, s1, 0, 0, 0);
        float p0r0 = exp2f(s0[0]), p0r1 = exp2f(s0[1]), p0r2 = exp2f(s0[2]), p0r3 = exp2f(s0[3]);
        float p1r0 = exp2f(s1[0]), p1r1 = exp2f(s1[1]), p1r2 = exp2f(s1[2]), p1r3 = exp2f(s1[3]);
        ls += (p0r0 + p0r1) + (p0r2 + p0r3) + (p1r0 + p1r1) + (p1r2 + p1r3);
        uint2 w0, w1;
        w0.x = pack2bf(p0r0, p0r1); w0.y = pack2bf(p0r2, p0r3);
        w1.x = pack2bf(p1r0, p1r1); w1.y = pack2bf(p1r2, p1r3);
        *(uint2*)(ptw + m * APT + quad * 4)      = w0;   // j local quad*4..+3
        *(uint2*)(ptw + m * APT + 16 + quad * 4) = w1;   // j local 16+quad*4..
        short8 av = ld8(vt + m * AVT + jl + quad * 8);
        short8 pb = ld8(ptw + m * APT + quad * 8);
        o = __builtin_amdgcn_mfma_f32_16x16x32_bf16(av, pb, o, 0, 0, 0);
    }
    // l for q=m: sum over quads
    ls += __shfl_xor(ls, 16, 64);
    ls += __shfl_xor(ls, 32, 64);
    size_t pbase = ((size_t)(bh * 6 + js) * 16) * NSP;
    #pragma unroll
    for (int r = 0; r < 4; r++)
        po[pbase + (size_t)(quad * 4 + r) * NSP + q0 + m] = o[r];
    if (quad == 0) pl[(size_t)(bh * 6 + js) * NSP + q0 + m] = ls;
}

// ======= attention merge ===================================================
__global__ void attn_merge_kernel(const float* __restrict__ po,
                                  const float* __restrict__ pl,
                                  float* __restrict__ out) {
    int bh = blockIdx.x;
    int b = bh >> 3, h = bh & 7;
    int q = blockIdx.y * 64 + (threadIdx.x & 63);
    int d0 = (threadIdx.x >> 6) * 4;
    float l = 0.f;
    #pragma unroll
    for (int js = 0; js < 6; js++) l += pl[(size_t)(bh * 6 + js) * NSP + q];
    float inv = 1.f / l;
    #pragma unroll
    for (int r = 0; r < 4; r++) {
        int d = d0 + r;
        float s = 0.f;
        #pragma unroll
        for (int js = 0; js < 6; js++)
            s += po[((size_t)(bh * 6 + js) * 16 + d) * NSP + q];
        out[((size_t)b * 128 + h * 16 + d) * NSP + q] = s * inv;
    }
}

// ======= shuffle attn: gates + gn stats from raw per-channel stats =========
__global__ void sfold_kernel(const float* __restrict__ rawstats,
                             const float* __restrict__ cw1, const float* __restrict__ cw2,
                             float* __restrict__ gate0, float* __restrict__ gnstat) {
    int bg = blockIdx.x;
    int b = bg >> 2, g = bg & 3;
    __shared__ float sp[16], sh[4];
    int t = threadIdx.x;
    if (t < 16) sp[t] = rawstats[(b * 128 + g * 32 + t) * 2] / (float)NSP;
    __syncthreads();
    if (t < 4) {
        float a = 0.f;
        for (int j = 0; j < 16; j++) a = fmaf(cw1[t * 16 + j], sp[j], a);
        sh[t] = a / (1.f + __expf(-a));
    }
    __syncthreads();
    if (t < 16) {
        float a = 0.f;
        for (int r = 0; r < 4; r++) a = fmaf(cw2[t * 4 + r], sh[r], a);
        gate0[bg * 16 + t] = 1.f / (1.f + __expf(-a));
    }
    if (t < 2) {
        float S = 0.f, S2 = 0.f;
        for (int k = 0; k < 8; k++) {
            int c = g * 32 + 16 + t * 8 + k;
            S  += rawstats[(b * 128 + c) * 2];
            S2 += rawstats[(b * 128 + c) * 2 + 1];
        }
        float N = 8.f * NSP;
        float mean = S / N, var = S2 / N - mean * mean;
        gnstat[(bg * 2 + t) * 2]     = mean;
        gnstat[(bg * 2 + t) * 2 + 1] = rsqrtf(var + 1e-5f);
    }
}

// ======= shuffle attn: final gating + channel shuffle ----------------------
__global__ void sfinal_kernel(const float* __restrict__ X,
                              const float* __restrict__ gate0,
                              const float* __restrict__ stats,
                              const float* __restrict__ gng,
                              const float* __restrict__ gnb,
                              const float* __restrict__ sw,
                              float* __restrict__ out) {
    int bg = blockIdx.x;
    int b = bg >> 2, g = bg & 3;
    __shared__ float swl[256];
    for (int i = threadIdx.x; i < 256; i += 64) swl[i] = sw[i];
    __syncthreads();
    int n = blockIdx.y * 64 + threadIdx.x;
    const float* xb = X + (size_t)b * 128 * NSP;
    #pragma unroll
    for (int j = 0; j < 16; j++) {
        float v = xb[(size_t)(g * 32 + j) * NSP + n] * gate0[bg * 16 + j];
        int k = g * 16 + j;
        int cp = (k % 32) * 4 + (k / 32);
        out[((size_t)b * 128 + cp) * NSP + n] = v;
    }
    float sgn[16];
    #pragma unroll
    for (int j = 0; j < 16; j++) {
        int grp = j >> 3;
        float mean = stats[(bg * 2 + grp) * 2];
        float rstd = stats[(bg * 2 + grp) * 2 + 1];
        float xv = xb[(size_t)(g * 32 + 16 + j) * NSP + n];
        sgn[j] = (xv - mean) * rstd * gng[j] + gnb[j];
    }
    #pragma unroll
    for (int j = 0; j < 16; j++) {
        float a = 0.f;
        #pragma unroll
        for (int jp = 0; jp < 16; jp++) a = fmaf(swl[j * 16 + jp], sgn[jp], a);
        float v = (1.f / (1.f + __expf(-a))) * xb[(size_t)(g * 32 + 16 + j) * NSP + n];
        int k = 64 + g * 16 + j;
        int cp = (k % 32) * 4 + (k / 32);
        out[((size_t)b * 128 + cp) * NSP + n] = v;
    }
}

// ===========================================================================
extern "C" void kernel_launch(void* const* d_in, const int* in_sizes, int n_in,
                              void* d_out, int out_size, void* d_ws, size_t ws_size,
                              hipStream_t stream) {
    const float* x     = (const float*)d_in[0];
    const float* m1_ew = (const float*)d_in[1];
    const float* m1_g1 = (const float*)d_in[2];
    const float* m1_b1 = (const float*)d_in[3];
    const float* m1_dw = (const float*)d_in[4];
    const float* m1_g2 = (const float*)d_in[5];
    const float* m1_b2 = (const float*)d_in[6];
    const float* m1_sw1= (const float*)d_in[7];
    const float* m1_sb1= (const float*)d_in[8];
    const float* m1_sw2= (const float*)d_in[9];
    const float* m1_sb2= (const float*)d_in[10];
    const float* m1_pw = (const float*)d_in[11];
    const float* m1_g3 = (const float*)d_in[12];
    const float* m1_b3 = (const float*)d_in[13];
    const float* m2_ew = (const float*)d_in[14];
    const float* m2_g1 = (const float*)d_in[15];
    const float* m2_b1 = (const float*)d_in[16];
    const float* m2_dw = (const float*)d_in[17];
    const float* m2_g2 = (const float*)d_in[18];
    const float* m2_b2 = (const float*)d_in[19];
    const float* m2_sw1= (const float*)d_in[20];
    const float* m2_sb1= (const float*)d_in[21];
    const float* m2_sw2= (const float*)d_in[22];
    const float* m2_sb2= (const float*)d_in[23];
    const float* m2_pw = (const float*)d_in[24];
    const float* m2_g3 = (const float*)d_in[25];
    const float* m2_b3 = (const float*)d_in[26];
    const float* t_n1g = (const float*)d_in[27];
    const float* t_n1b = (const float*)d_in[28];
    const float* t_qkv = (const float*)d_in[29];
    const float* t_pw  = (const float*)d_in[30];
    const float* t_pb  = (const float*)d_in[31];
    const float* t_n2g = (const float*)d_in[32];
    const float* t_n2b = (const float*)d_in[33];
    const float* t_mw1 = (const float*)d_in[34];
    const float* t_mb1 = (const float*)d_in[35];
    const float* t_mw2 = (const float*)d_in[36];
    const float* t_mb2 = (const float*)d_in[37];
    const float* s_cw1 = (const float*)d_in[38];
    const float* s_cw2 = (const float*)d_in[39];
    const float* s_gng = (const float*)d_in[40];
    const float* s_gnb = (const float*)d_in[41];
    const float* s_sw  = (const float*)d_in[42];

    float* out = (float*)d_out;

    float* ws = (float*)d_ws;
    float* bufA   = ws;                                 // 2*512*NSP (also attn po)
    float* bufB   = bufA + (size_t)BB * 512 * NSP;      // 2*512*NSP
    float* bufX   = bufB + (size_t)BB * 512 * NSP;      // 2*128*NSP
    float* bufY   = bufX + (size_t)BB * 128 * NSP;      // 2*128*NSP
    float* bufQKV = bufY + (size_t)BB * 128 * NSP;      // 2*384*NSP (also k-split partials)
    float* pl     = bufQKV + (size_t)BB * 384 * NSP;    // 16*6*NSP
    float* small  = pl + (size_t)16 * 6 * NSP;
    float* se_s    = small;           // 1024
    float* se_gate = small + 1024;    // 1024
    float* rawst   = small + 2048;    // 512  (m2proj stats, direct)
    float* rawst2  = small + 2560;    // 512  (attn-proj stats, atomic)
    float* rawst3  = small + 3072;    // 512  (mlp2 stats, direct)
    float* scale1  = small + 3584;    // 256
    float* scale2  = small + 3840;    // 256
    float* biasb1  = small + 4096;    // 768
    float* biasb2  = small + 4864;    // 1024
    float* gate0   = small + 5888;    // 128
    float* gnstat  = small + 6016;    // 32
    float* po   = bufA;                          // attn partials 16*6*16*NSP
    float* pk0  = bufQKV;                        // k-split partial 0
    float* pk1  = bufQKV + (size_t)BB * 128 * NSP;   // k-split partial 1

    dim3 blk(256);

    hipMemsetAsync(rawst2, 0, 512 * sizeof(float), stream);

    // ---------------- MBConv1: 64 -> 256 -> 128 ----------------
    convn1_kernel<<<dim3(BB * 64, 8, 1), blk, 64 * 16, stream>>>(
        x, m1_ew, nullptr, nullptr, nullptr, nullptr, bufA, nullptr, 64, 256, 0);
    indw_kernel<<<BB * 256, blk, 0, stream>>>(bufA, m1_g1, m1_b1, m1_dw, m1_g2, m1_b2, bufB, se_s, 256);
    se_kernel<<<BB, blk, 0, stream>>>(se_s, m1_sw1, m1_sb1, m1_sw2, m1_sb2, se_gate, 256, 64);
    convn1_kernel<<<dim3(BB * 32, 8, 2), blk, 128 * 16, stream>>>(
        bufB, m1_pw, nullptr, nullptr, se_gate, nullptr, pk0, nullptr, 256, 128, 0);
    post2_kernel<<<BB * 128, blk, 0, stream>>>(pk0, pk1, nullptr, m1_g3, m1_b3, 1,
                                               nullptr, bufX, nullptr, 128);

    // ---------------- MBConv2: 128 -> 512 -> 128 (+res) ----------------
    convn1_kernel<<<dim3(BB * 128, 8, 1), blk, 128 * 16, stream>>>(
        bufX, m2_ew, nullptr, nullptr, nullptr, nullptr, bufA, nullptr, 128, 512, 0);
    indw_kernel<<<BB * 512, blk, 0, stream>>>(bufA, m2_g1, m2_b1, m2_dw, m2_g2, m2_b2, bufB, se_s, 512);
    se_kernel<<<BB, blk, 0, stream>>>(se_s, m2_sw1, m2_sb1, m2_sw2, m2_sb2, se_gate, 512, 128);
    convn1_kernel<<<dim3(BB * 32, 8, 2), blk, 256 * 16, stream>>>(
        bufB, m2_pw, nullptr, nullptr, se_gate, nullptr, pk0, nullptr, 512, 128, 0);
    post2_kernel<<<BB * 128, blk, 0, stream>>>(pk0, pk1, nullptr, m2_g3, m2_b3, 1,
                                               bufX, bufX, rawst, 128);

    // ---------------- Transformer ----------------
    gfold_kernel<<<BB * 6, dim3(64), 0, stream>>>(rawst, t_n1g, t_n1b, t_qkv, nullptr, scale1, biasb1, 128, 384, 4);
    convn1_kernel<<<dim3(BB * 96, 8, 1), blk, 128 * 16, stream>>>(
        bufX, t_qkv, nullptr, biasb1, scale1, nullptr, bufQKV, nullptr, 128, 384, 0);
    attn_split_kernel<<<dim3(16, 27, 6), blk, 0, stream>>>(bufQKV, po, pl);
    attn_merge_kernel<<<dim3(16, 27), blk, 0, stream>>>(po, pl, bufY);
    convn1_kernel<<<dim3(BB * 32, 8, 1), blk, 128 * 16, stream>>>(
        bufY, t_pw, t_pb, nullptr, nullptr, bufX, bufX, rawst2, 128, 128, 0);
    gfold_kernel<<<BB * 8, dim3(64), 0, stream>>>(rawst2, t_n2g, t_n2b, t_mw1, t_mb1, scale2, biasb2, 128, 512, 4);
    convn1_kernel<<<dim3(BB * 128, 8, 1), blk, 128 * 16, stream>>>(
        bufX, t_mw1, nullptr, biasb2, scale2, nullptr, bufA, nullptr, 128, 512, 2);
    convn1_kernel<<<dim3(BB * 32, 8, 2), blk, 256 * 16, stream>>>(
        bufA, t_mw2, nullptr, nullptr, nullptr, nullptr, pk0, nullptr, 512, 128, 0);
    post2_kernel<<<BB * 128, blk, 0, stream>>>(pk0, pk1, t_mb2, nullptr, nullptr, 0,
                                               bufX, bufX, rawst3, 128);

    // ---------------- Shuffle attention ----------------
    sfold_kernel<<<BB * 4, dim3(64), 0, stream>>>(rawst3, s_cw1, s_cw2, gate0, gnstat);
    sfinal_kernel<<<dim3(BB * 4, 27), dim3(64), 0, stream>>>(bufX, gate0, gnstat, s_gng, s_gnb, s_sw, out);
}